// Round 14
// baseline (143.853 us; speedup 1.0000x reference)
//
#include <hip/hip_runtime.h>
#include <hip/hip_bf16.h>

#define NV 40962
#define NK 9
#define CIN 32
#define COUT 32
#define NBS 4
#define VT 256                 // transpose v-tile
#define TP 260                 // transpose LDS row stride (dwords)
#define NT 2561                // v-tiles of 16 in main kernel
#define PGRID 768              // persistent blocks (3 per CU, all co-resident)
#define NV81 (NV * 81)
#define NV9  (NV * 9)

typedef __attribute__((ext_vector_type(8))) short bf16x8;
typedef __attribute__((ext_vector_type(4))) float f32x4;
typedef __attribute__((ext_vector_type(2))) float f32x2;

// ---- packed f32 FMA/MUL with src0 broadcast from pair half (VOP3P op_sel).
#define PKFMA_L(A, G, R) asm("v_pk_fma_f32 %0, %1, %2, %0 op_sel:[0,0,0] op_sel_hi:[0,1,1]" : "+v"(A) : "v"(G), "v"(R))
#define PKFMA_H(A, G, R) asm("v_pk_fma_f32 %0, %1, %2, %0 op_sel:[1,0,0] op_sel_hi:[1,1,1]" : "+v"(A) : "v"(G), "v"(R))
#define PKMUL_L(A, G, R) asm("v_pk_mul_f32 %0, %1, %2 op_sel:[0,0] op_sel_hi:[0,1]" : "=v"(A) : "v"(G), "v"(R))
#define PKMUL_H(A, G, R) asm("v_pk_mul_f32 %0, %1, %2 op_sel:[1,0] op_sel_hi:[1,1]" : "=v"(A) : "v"(G), "v"(R))

#define ACC(cc, j) ((j) == 8 ? acc8[cc] : (((j) & 1) ? acc2[cc][(j) >> 1].y \
                                                     : acc2[cc][(j) >> 1].x))

// f32 pair -> packed bf16 dword (a=low), via v_cvt_pk_bf16_f32 (RNE)
__device__ __forceinline__ unsigned pkbf(float a, float b) {
    union { __hip_bfloat162 h2; unsigned u; } cv;
    cv.h2 = __float22bfloat162_rn(make_float2(a, b));
    return cv.u;
}

// LDS-only barrier (no vmcnt drain)
__device__ __forceinline__ void bar_lgkm() {
    asm volatile("s_waitcnt lgkmcnt(0)\n\ts_barrier" ::: "memory");
}

// ---------------------------------------------------------------------------
// Kernel 1: x [128 rows=(b*32+c)][V] f32 -> xt [v][b0|b1|b2|b3 x 32ch] bf16
// ---------------------------------------------------------------------------
__global__ void __launch_bounds__(256) transpose_x_bf16(
    const float* __restrict__ x, unsigned* __restrict__ xtw)
{
    __shared__ unsigned T[16 * TP];
    const int b  = blockIdx.x & 3;
    const int v0 = (blockIdx.x >> 2) * VT;
    const int t  = threadIdx.x;
    const int w  = t >> 6;
    const int L  = t & 63;
    const bool full = (v0 + VT <= NV);

    #pragma unroll
    for (int i = 0; i < 4; ++i) {
        const int q = w + 4 * i;
        const float* rowA = x + (size_t)(b * 32 + 2 * q) * NV;
        const float* rowB = rowA + NV;
        #pragma unroll
        for (int h = 0; h < 2; ++h) {
            const int vl = 128 * h + 2 * L;
            float2 a, c;
            if (full) {
                a = *(const float2*)(rowA + v0 + vl);
                c = *(const float2*)(rowB + v0 + vl);
            } else {
                const int v = v0 + vl;
                a.x = (v     < NV) ? rowA[v]     : 0.0f;
                a.y = (v + 1 < NV) ? rowA[v + 1] : 0.0f;
                c.x = (v     < NV) ? rowB[v]     : 0.0f;
                c.y = (v + 1 < NV) ? rowB[v + 1] : 0.0f;
            }
            uint2 d;
            d.x = pkbf(a.x, c.x);
            d.y = pkbf(a.y, c.y);
            *(uint2*)&T[q * TP + vl] = d;
        }
    }
    __syncthreads();

    #pragma unroll
    for (int i = 0; i < 4; ++i) {
        const int vl = i * 64 + w * 16 + (L >> 2);
        const int u4 = L & 3;
        const int v  = v0 + vl;
        if (v < NV) {
            uint4 d;
            d.x = T[(4 * u4 + 0) * TP + vl];
            d.y = T[(4 * u4 + 1) * TP + vl];
            d.z = T[(4 * u4 + 2) * TP + vl];
            d.w = T[(4 * u4 + 3) * TP + vl];
            *(uint4*)&xtw[(size_t)v * 64 + b * 16 + 4 * u4] = d;
        }
    }
}

// ---------------------------------------------------------------------------
// Kernel 2: conv weight f32 [o][c][j] -> bf16 [o][k=c*9+j]  (GEMM K-order)
// ---------------------------------------------------------------------------
__global__ void __launch_bounds__(256) convert_w_bf16(
    const float* __restrict__ w, unsigned short* __restrict__ wbf)
{
    const int i = blockIdx.x * 256 + threadIdx.x;
    if (i < COUT * CIN * NK) {
        unsigned u = __float_as_uint(w[i]);
        wbf[i] = (unsigned short)((u + 0x7FFFu + ((u >> 16) & 1u)) >> 16);
    }
}

// itp global load (1296 dwords / tile), per-element guarded
__device__ __forceinline__ void load_itp(float itpv[3],
                                         const float* __restrict__ itp,
                                         int tile, int t)
{
    const size_t base = (size_t)tile * 1296;
    #pragma unroll
    for (int i = 0; i < 3; ++i) {
        const int o = i * 512 + t;
        itpv[i] = (o < 1296 && base + o < (size_t)NV81) ? itp[base + o] : 0.0f;
    }
}

// stage 1296 itp dwords into padded LDS [vl][k][12]
__device__ __forceinline__ void stage_itp(float* __restrict__ buf,
                                          const float itpv[3], int t)
{
    #pragma unroll
    for (int i = 0; i < 3; ++i) {
        const int o = i * 512 + t;
        if (o < 1296) {
            const int vl = o / 81;
            const int r  = o - vl * 81;
            const int kk = r / 9;
            const int jj = r - kk * 9;
            buf[vl * 108 + kk * 12 + jj] = itpv[i];
        }
    }
}

// idx global load (144 ints / tile via threads t<144), guarded
__device__ __forceinline__ int load_idx(const int* __restrict__ index,
                                        int tile, int t)
{
    int r = 0;
    if (t < 144) {
        const size_t base = (size_t)tile * 144 + t;
        r = (base < (size_t)NV9) ? index[base] : 0;
    }
    return r;
}

// ---------------------------------------------------------------------------
// Kernel 3: persistent pipelined fused kernel, 512 thr, 3 blocks/CU.
// r14 wave remap: wave w = (b = w>>1, half = w&1); lane = (vloc, quad).
// Gather addr = nbr*256B + b*64 + half*32 + quad*8 -> 16 lines/inst (was 64).
// W from global wbf (L1-hot, no Wlds) -> LDS 45KB -> 3 blocks/CU.
// Thread ch-range c0 = half*16+quad*4 (4 ch), col = b*16+vloc.
// ---------------------------------------------------------------------------
__global__ void __launch_bounds__(512) sparse_conv_mfma(
    const unsigned short* __restrict__ xt, const int* __restrict__ index,
    const float* __restrict__ itp, const unsigned short* __restrict__ wbf,
    const float* __restrict__ bias, float* __restrict__ out)
{
    __shared__ unsigned Alds8[72 * 64 * 2];        // 36864 B: plane p = k 4p..4p+3
    __shared__ float itp_s[16 * 108];              //  6912 B
    __shared__ int   idx_s[2][144];                //  1152 B
    __shared__ unsigned long long nzb[8];          //    64 B

    const int t    = threadIdx.x;
    const int wv   = t >> 6;                 // wave id
    const int b    = wv >> 1;                // batch
    const int half = wv & 1;                 // ch/o half
    const int lane = t & 63;
    const int vloc = lane & 15;
    const int quad = lane >> 4;
    const int col  = b * 16 + vloc;
    // gather base: shorts; row = nbr*128 shorts
    const unsigned short* gb = xt + b * 32 + half * 16 + quad * 4;

    // ---------------- prologue ----------------
    int tile = blockIdx.x;
    {
        const int i0 = load_idx(index, tile, t);
        const int i1 = load_idx(index, min(tile + PGRID, NT - 1), t);
        if (t < 144) { idx_s[0][t] = i0; idx_s[1][t] = i1; }
    }
    float itpv[3];
    load_itp(itpv, itp, tile, t);
    stage_itp(itp_s, itpv, t);
    __syncthreads();                         // idx_s/itp_s visible

    uint2 gath[NK];
    #pragma unroll
    for (int k = 0; k < NK; ++k) {           // gathers(t0)
        const int nbr = idx_s[0][vloc * 9 + k];
        gath[k] = *(const uint2*)(gb + (size_t)nbr * 128);
    }
    load_itp(itpv, itp, min(tile + PGRID, NT - 1), t);
    int idxn = load_idx(index, min(tile + 2 * PGRID, NT - 1), t);
    int cur = 0;

    for (; tile < NT; tile += PGRID) {
        // ---- B: consume gath(t)+itp_s -> interp; interleave gath(t+1) issue
        unsigned nzbits = 0;
        f32x2 acc2[4][4];                    // [cc][j-pair]
        float acc8[4];                       // j = 8
        const float* ib = &itp_s[vloc * 108];

        #pragma unroll
        for (int k = 0; k < 4; ++k) {
            const uint2 gk = gath[k];
            nzbits |= (gk.x | gk.y) & 0x7FFF7FFFu;
            f32x2 gp01, gp23;
            gp01.x = __uint_as_float(gk.x << 16);
            gp01.y = __uint_as_float(gk.x & 0xFFFF0000u);
            gp23.x = __uint_as_float(gk.y << 16);
            gp23.y = __uint_as_float(gk.y & 0xFFFF0000u);
            const float* ir = ib + k * 12;
            f32x2 rp[4];
            rp[0] = *(const f32x2*)ir;       rp[1] = *(const f32x2*)(ir + 2);
            rp[2] = *(const f32x2*)(ir + 4); rp[3] = *(const f32x2*)(ir + 6);
            const float r8 = ir[8];
            if (k == 0) {
                #pragma unroll
                for (int jp = 0; jp < 4; ++jp) {
                    PKMUL_L(acc2[0][jp], gp01, rp[jp]);
                    PKMUL_H(acc2[1][jp], gp01, rp[jp]);
                    PKMUL_L(acc2[2][jp], gp23, rp[jp]);
                    PKMUL_H(acc2[3][jp], gp23, rp[jp]);
                }
                acc8[0] = gp01.x * r8; acc8[1] = gp01.y * r8;
                acc8[2] = gp23.x * r8; acc8[3] = gp23.y * r8;
            } else {
                #pragma unroll
                for (int jp = 0; jp < 4; ++jp) {
                    PKFMA_L(acc2[0][jp], gp01, rp[jp]);
                    PKFMA_H(acc2[1][jp], gp01, rp[jp]);
                    PKFMA_L(acc2[2][jp], gp23, rp[jp]);
                    PKFMA_H(acc2[3][jp], gp23, rp[jp]);
                }
                acc8[0] += gp01.x * r8; acc8[1] += gp01.y * r8;
                acc8[2] += gp23.x * r8; acc8[3] += gp23.y * r8;
            }
        }
        #pragma unroll
        for (int k = 0; k < 4; ++k) {        // reissue k0-3 early
            const int nbr = idx_s[cur ^ 1][vloc * 9 + k];
            gath[k] = *(const uint2*)(gb + (size_t)nbr * 128);
        }
        #pragma unroll
        for (int k = 4; k < 9; ++k) {
            const uint2 gk = gath[k];
            nzbits |= (gk.x | gk.y) & 0x7FFF7FFFu;
            f32x2 gp01, gp23;
            gp01.x = __uint_as_float(gk.x << 16);
            gp01.y = __uint_as_float(gk.x & 0xFFFF0000u);
            gp23.x = __uint_as_float(gk.y << 16);
            gp23.y = __uint_as_float(gk.y & 0xFFFF0000u);
            const float* ir = ib + k * 12;
            f32x2 rp[4];
            rp[0] = *(const f32x2*)ir;       rp[1] = *(const f32x2*)(ir + 2);
            rp[2] = *(const f32x2*)(ir + 4); rp[3] = *(const f32x2*)(ir + 6);
            const float r8 = ir[8];
            #pragma unroll
            for (int jp = 0; jp < 4; ++jp) {
                PKFMA_L(acc2[0][jp], gp01, rp[jp]);
                PKFMA_H(acc2[1][jp], gp01, rp[jp]);
                PKFMA_L(acc2[2][jp], gp23, rp[jp]);
                PKFMA_H(acc2[3][jp], gp23, rp[jp]);
            }
            acc8[0] += gp01.x * r8; acc8[1] += gp01.y * r8;
            acc8[2] += gp23.x * r8; acc8[3] += gp23.y * r8;
        }
        #pragma unroll
        for (int k = 4; k < 9; ++k) {
            const int nbr = idx_s[cur ^ 1][vloc * 9 + k];
            gath[k] = *(const uint2*)(gb + (size_t)nbr * 128);
        }

        // pack: thread's k = 9*c0 + 4*i2 .. +4 -> plane 36*half+9*quad+i2
        #pragma unroll
        for (int i2 = 0; i2 < 9; ++i2) {
            const int k0 = 4 * i2;
            const int pl = 36 * half + 9 * quad + i2;
            uint2 d;
            d.x = pkbf(ACC(k0 / 9, k0 % 9),
                       ACC((k0 + 1) / 9, (k0 + 1) % 9));
            d.y = pkbf(ACC((k0 + 2) / 9, (k0 + 2) % 9),
                       ACC((k0 + 3) / 9, (k0 + 3) % 9));
            *(uint2*)&Alds8[(pl * 64 + col) * 2] = d;
        }
        // nz: OR over quads in-wave, publish per-wave ballot
        unsigned nzw = nzbits;
        nzw |= __shfl_xor(nzw, 16);
        nzw |= __shfl_xor(nzw, 32);
        const unsigned long long bal = __ballot(nzw != 0);
        if (lane == 0) nzb[wv] = bal;

        bar_lgkm();                          // E1: Alds8/nzb visible

        // ---- D: MFMA + store; pipeline maintenance ----
        {
            f32x4 a0 = {0.f, 0.f, 0.f, 0.f};
            #pragma unroll
            for (int ks = 0; ks < 9; ++ks) {
                const int p0 = ks * 8 + quad * 2;
                const uint2 l2 = *(const uint2*)&Alds8[(p0 * 64 + col) * 2];
                const uint2 h2 = *(const uint2*)&Alds8[((p0 + 1) * 64 + col) * 2];
                union { uint4 u; bf16x8 v; } f;
                f.u.x = l2.x; f.u.y = l2.y; f.u.z = h2.x; f.u.w = h2.y;
                const int ko = ks * 32 + quad * 8;
                const bf16x8 wa = *(const bf16x8*)(wbf + (half * 16 + vloc) * 288 + ko);
                a0 = __builtin_amdgcn_mfma_f32_16x16x32_bf16(wa, f.v, a0, 0, 0, 0);
            }

            const unsigned long long nz = nzb[2 * b] | nzb[2 * b + 1];
            const float m = ((nz >> vloc) & 1ull) ? 1.0f : 0.0f;
            const int vv = tile * 16 + vloc;
            if (vv < NV) {
                float* outb = out + (size_t)b * (COUT * NV) + vv;
                #pragma unroll
                for (int r = 0; r < 4; ++r) {
                    const int o = half * 16 + quad * 4 + r;
                    outb[(size_t)o * NV] = (a0[r] + bias[o]) * m;
                }
            }
        }
        stage_itp(itp_s, itpv, t);           // itp(t+1); safe after E1
        if (t < 144) idx_s[cur][t] = idxn;   // idx(t+2)
        load_itp(itpv, itp, min(tile + 2 * PGRID, NT - 1), t);
        idxn = load_idx(index, min(tile + 3 * PGRID, NT - 1), t);

        bar_lgkm();                          // E2: Alds reads done before reuse
        cur ^= 1;
    }
}

// ---------------------------------------------------------------------------
extern "C" void kernel_launch(void* const* d_in, const int* in_sizes, int n_in,
                              void* d_out, int out_size, void* d_ws, size_t ws_size,
                              hipStream_t stream)
{
    const float* x     = (const float*)d_in[0];
    const int*   index = (const int*)  d_in[1];
    const float* itp   = (const float*)d_in[2];
    const float* w     = (const float*)d_in[3];
    const float* bias  = (const float*)d_in[4];
    float*       out   = (float*)d_out;

    unsigned short* xt  = (unsigned short*)d_ws;                 // 10.5 MB
    unsigned short* wbf = (unsigned short*)((char*)d_ws + (size_t)NV * 256);

    hipLaunchKernelGGL(convert_w_bf16, dim3((COUT * CIN * NK + 255) / 256),
                       dim3(256), 0, stream, w, wbf);
    const int vtiles = (NV + VT - 1) / VT;   // 161
    hipLaunchKernelGGL(transpose_x_bf16, dim3(vtiles * NBS), dim3(256), 0,
                       stream, x, (unsigned*)xt);
    hipLaunchKernelGGL(sparse_conv_mfma, dim3(PGRID), dim3(512), 0,
                       stream, xt, index, itp, wbf, bias, out);
}

// Round 15
// 125.578 us; speedup vs baseline: 1.1455x; 1.1455x over previous
//
#include <hip/hip_runtime.h>
#include <hip/hip_bf16.h>

#define NV 40962
#define NK 9
#define CIN 32
#define COUT 32
#define NBS 4
#define VT 256                 // transpose v-tile
#define TP 260                 // transpose LDS row stride (dwords)
#define NT 2561                // v-tiles of 16 in main kernel
#define NV81 (NV * 81)
#define NV9  (NV * 9)

typedef __attribute__((ext_vector_type(8))) short bf16x8;
typedef __attribute__((ext_vector_type(4))) float f32x4;
typedef __attribute__((ext_vector_type(2))) float f32x2;

// ---- packed f32 FMA/MUL, src0 broadcast from pair half (VOP3P op_sel)
#define PKFMA_L(A, G, R) asm("v_pk_fma_f32 %0, %1, %2, %0 op_sel:[0,0,0] op_sel_hi:[0,1,1]" : "+v"(A) : "v"(G), "v"(R))
#define PKFMA_H(A, G, R) asm("v_pk_fma_f32 %0, %1, %2, %0 op_sel:[1,0,0] op_sel_hi:[1,1,1]" : "+v"(A) : "v"(G), "v"(R))
#define PKMUL_L(A, G, R) asm("v_pk_mul_f32 %0, %1, %2 op_sel:[0,0] op_sel_hi:[0,1]" : "=v"(A) : "v"(G), "v"(R))
#define PKMUL_H(A, G, R) asm("v_pk_mul_f32 %0, %1, %2 op_sel:[1,0] op_sel_hi:[1,1]" : "=v"(A) : "v"(G), "v"(R))

#define ACC(cc, j) ((j) == 8 ? acc8[cc] : (((j) & 1) ? acc2[cc][(j) >> 1].y \
                                                     : acc2[cc][(j) >> 1].x))

// f32 pair -> packed bf16 dword (a=low), via v_cvt_pk_bf16_f32 (RNE)
__device__ __forceinline__ unsigned pkbf(float a, float b) {
    union { __hip_bfloat162 h2; unsigned u; } cv;
    cv.h2 = __float22bfloat162_rn(make_float2(a, b));
    return cv.u;
}

// ---------------------------------------------------------------------------
// Kernel 1: x [128 rows=(b*32+c)][V] f32 -> xt [v][b0|b1|b2|b3 x 32ch] bf16
// ---------------------------------------------------------------------------
__global__ void __launch_bounds__(256) transpose_x_bf16(
    const float* __restrict__ x, unsigned* __restrict__ xtw)
{
    __shared__ unsigned T[16 * TP];
    const int b  = blockIdx.x & 3;
    const int v0 = (blockIdx.x >> 2) * VT;
    const int t  = threadIdx.x;
    const int w  = t >> 6;
    const int L  = t & 63;
    const bool full = (v0 + VT <= NV);

    #pragma unroll
    for (int i = 0; i < 4; ++i) {
        const int q = w + 4 * i;
        const float* rowA = x + (size_t)(b * 32 + 2 * q) * NV;
        const float* rowB = rowA + NV;
        #pragma unroll
        for (int h = 0; h < 2; ++h) {
            const int vl = 128 * h + 2 * L;
            float2 a, c;
            if (full) {
                a = *(const float2*)(rowA + v0 + vl);
                c = *(const float2*)(rowB + v0 + vl);
            } else {
                const int v = v0 + vl;
                a.x = (v     < NV) ? rowA[v]     : 0.0f;
                a.y = (v + 1 < NV) ? rowA[v + 1] : 0.0f;
                c.x = (v     < NV) ? rowB[v]     : 0.0f;
                c.y = (v + 1 < NV) ? rowB[v + 1] : 0.0f;
            }
            uint2 d;
            d.x = pkbf(a.x, c.x);
            d.y = pkbf(a.y, c.y);
            *(uint2*)&T[q * TP + vl] = d;
        }
    }
    __syncthreads();

    #pragma unroll
    for (int i = 0; i < 4; ++i) {
        const int vl = i * 64 + w * 16 + (L >> 2);
        const int u4 = L & 3;
        const int v  = v0 + vl;
        if (v < NV) {
            uint4 d;
            d.x = T[(4 * u4 + 0) * TP + vl];
            d.y = T[(4 * u4 + 1) * TP + vl];
            d.z = T[(4 * u4 + 2) * TP + vl];
            d.w = T[(4 * u4 + 3) * TP + vl];
            *(uint4*)&xtw[(size_t)v * 64 + b * 16 + 4 * u4] = d;
        }
    }
}

// ---------------------------------------------------------------------------
// Kernel 2: conv weight f32 [o][c][j] -> bf16 wbf[o][k' = j*32 + c]
// (K-permuted GEMM order so B-frags can be built per-lane without LDS)
// ---------------------------------------------------------------------------
__global__ void __launch_bounds__(256) convert_w_bf16(
    const float* __restrict__ w, unsigned short* __restrict__ wbf)
{
    const int i = blockIdx.x * 256 + threadIdx.x;
    if (i < COUT * CIN * NK) {
        const int o = i / 288;
        const int r = i - o * 288;
        const int c = r / 9;
        const int j = r - c * 9;
        unsigned u = __float_as_uint(w[i]);
        wbf[o * 288 + j * 32 + c] =
            (unsigned short)((u + 0x7FFFu + ((u >> 16) & 1u)) >> 16);
    }
}

// ---------------------------------------------------------------------------
// Kernel 3: wave-autonomous fused kernel, NO A-tile LDS round-trip.
// Grid = NT blocks x 256 thr (4 waves); wave = batch b; lane = (vloc, quad).
// K' = j*32 + c  =>  lane's B-frag at step ks = interp[c=quad*8+jj][j=ks],
// jj=0..7 — exactly the 8 contiguous channels the lane gathers (16B/nbr)
// and interpolates itself. Two 4-ch halves keep interp acc at 36 VGPR.
// Single __syncthreads (Wlds/itp/idx staging); then waves run free:
// 18 gathers -> pk-fma interp -> pack frags in regs -> 18 MFMA (W from
// k'-ordered Wlds b128) -> shfl nz -> masked stores.
// ---------------------------------------------------------------------------
__global__ void __launch_bounds__(256) sparse_conv_mfma(
    const unsigned short* __restrict__ xt, const int* __restrict__ index,
    const float* __restrict__ itp, const unsigned short* __restrict__ wbf,
    const float* __restrict__ bias, float* __restrict__ out)
{
    __shared__ unsigned short Wlds[9 * 32 * 32];   // 18432 B, [j][o][c]
    __shared__ float itp_s[16 * 108];              //  6912 B, [vl][n][12]
    __shared__ int   idx_s[144];                   //   576 B

    const int t    = threadIdx.x;
    const int b    = t >> 6;                 // wave = batch
    const int lane = t & 63;
    const int vloc = lane & 15;
    const int quad = lane >> 4;
    const int tile = blockIdx.x;

    // bias -> regs (tile-invariant)
    float bs0[4], bs1[4];
    #pragma unroll
    for (int r = 0; r < 4; ++r) {
        bs0[r] = bias[quad * 4 + r];
        bs1[r] = bias[quad * 4 + 16 + r];
    }

    // stage Wlds: dst 16B-chunk n -> (j = n>>7, o = (n>>2)&31, cq = n&3)
    // src chunk in wbf (already k'-ordered) = o*36 + j*4 + cq
    #pragma unroll
    for (int r = 0; r < 5; ++r) {
        const int n = t + r * 256;
        if (n < 1152) {
            const int j  = n >> 7;
            const int o  = (n >> 2) & 31;
            const int cq = n & 3;
            ((uint4*)Wlds)[n] = ((const uint4*)wbf)[o * 36 + j * 4 + cq];
        }
    }
    if (t < 144) {
        const size_t bix = (size_t)tile * 144 + t;
        idx_s[t] = (bix < (size_t)NV9) ? index[bix] : 0;
    }
    {
        float itpv[6];
        const size_t base = (size_t)tile * 1296;
        #pragma unroll
        for (int i = 0; i < 6; ++i) {
            const int o = i * 256 + t;
            itpv[i] = (o < 1296 && base + o < (size_t)NV81) ? itp[base + o]
                                                            : 0.0f;
        }
        #pragma unroll
        for (int i = 0; i < 6; ++i) {
            const int o = i * 256 + t;
            if (o < 1296) {
                const int vl = o / 81;
                const int r2 = o - vl * 81;
                const int kk = r2 / 9;
                const int jj = r2 - kk * 9;
                itp_s[vl * 108 + kk * 12 + jj] = itpv[i];
            }
        }
    }
    __syncthreads();                         // the only barrier

    // neighbor ids (quad-broadcast LDS reads)
    int nbr[NK];
    #pragma unroll
    for (int n = 0; n < NK; ++n) nbr[n] = idx_s[vloc * 9 + n];

    // gathers: lane channels c = quad*8 .. quad*8+8, split in two uint2 halves
    const unsigned short* gbase = xt + b * 32 + quad * 8;
    uint2 g0[NK], g1[NK];
    #pragma unroll
    for (int n = 0; n < NK; ++n)
        g0[n] = *(const uint2*)(gbase + (size_t)nbr[n] * 128);
    #pragma unroll
    for (int n = 0; n < NK; ++n)
        g1[n] = *(const uint2*)(gbase + (size_t)nbr[n] * 128 + 4);

    unsigned frag[9][4];                     // B-frags, built in registers
    unsigned nzbits = 0;
    const float* ib = &itp_s[vloc * 108];

    #pragma unroll
    for (int h = 0; h < 2; ++h) {            // 4 channels per half
        f32x2 acc2[4][4];
        float acc8[4];
        #pragma unroll
        for (int n = 0; n < NK; ++n) {
            const uint2 gk = h ? g1[n] : g0[n];
            nzbits |= (gk.x | gk.y) & 0x7FFF7FFFu;
            f32x2 gp01, gp23;
            gp01.x = __uint_as_float(gk.x << 16);
            gp01.y = __uint_as_float(gk.x & 0xFFFF0000u);
            gp23.x = __uint_as_float(gk.y << 16);
            gp23.y = __uint_as_float(gk.y & 0xFFFF0000u);
            const float* ir = ib + n * 12;
            const f32x4 ra = *(const f32x4*)ir;
            const f32x4 rb = *(const f32x4*)(ir + 4);
            const float r8 = ir[8];
            f32x2 rp[4];
            rp[0] = __builtin_shufflevector(ra, ra, 0, 1);
            rp[1] = __builtin_shufflevector(ra, ra, 2, 3);
            rp[2] = __builtin_shufflevector(rb, rb, 0, 1);
            rp[3] = __builtin_shufflevector(rb, rb, 2, 3);
            if (n == 0) {
                #pragma unroll
                for (int jp = 0; jp < 4; ++jp) {
                    PKMUL_L(acc2[0][jp], gp01, rp[jp]);
                    PKMUL_H(acc2[1][jp], gp01, rp[jp]);
                    PKMUL_L(acc2[2][jp], gp23, rp[jp]);
                    PKMUL_H(acc2[3][jp], gp23, rp[jp]);
                }
                acc8[0] = gp01.x * r8; acc8[1] = gp01.y * r8;
                acc8[2] = gp23.x * r8; acc8[3] = gp23.y * r8;
            } else {
                #pragma unroll
                for (int jp = 0; jp < 4; ++jp) {
                    PKFMA_L(acc2[0][jp], gp01, rp[jp]);
                    PKFMA_H(acc2[1][jp], gp01, rp[jp]);
                    PKFMA_L(acc2[2][jp], gp23, rp[jp]);
                    PKFMA_H(acc2[3][jp], gp23, rp[jp]);
                }
                acc8[0] += gp01.x * r8; acc8[1] += gp01.y * r8;
                acc8[2] += gp23.x * r8; acc8[3] += gp23.y * r8;
            }
        }
        // pack this half's 4 channels into frag dwords 2h, 2h+1
        #pragma unroll
        for (int ks = 0; ks < 9; ++ks) {
            frag[ks][2 * h]     = pkbf(ACC(0, ks), ACC(1, ks));
            frag[ks][2 * h + 1] = pkbf(ACC(2, ks), ACC(3, ks));
        }
    }

    // nz over all 32 channels of col vloc (quads within the wave)
    unsigned nzw = nzbits;
    nzw |= __shfl_xor(nzw, 16);
    nzw |= __shfl_xor(nzw, 32);

    // MFMA: 9 K'-steps x 2 o-halves; A = Wlds[j][o][c] b128 reads
    f32x4 c0 = {0.f, 0.f, 0.f, 0.f};
    f32x4 c1 = {0.f, 0.f, 0.f, 0.f};
    #pragma unroll
    for (int ks = 0; ks < 9; ++ks) {
        union { uint4 u; bf16x8 v; } bfr;
        bfr.u.x = frag[ks][0]; bfr.u.y = frag[ks][1];
        bfr.u.z = frag[ks][2]; bfr.u.w = frag[ks][3];
        const bf16x8 wa0 =
            *(const bf16x8*)&Wlds[(ks * 32 + vloc) * 32 + quad * 8];
        const bf16x8 wa1 =
            *(const bf16x8*)&Wlds[(ks * 32 + vloc + 16) * 32 + quad * 8];
        c0 = __builtin_amdgcn_mfma_f32_16x16x32_bf16(wa0, bfr.v, c0, 0, 0, 0);
        c1 = __builtin_amdgcn_mfma_f32_16x16x32_bf16(wa1, bfr.v, c1, 0, 0, 0);
    }

    // epilogue: C col = vloc (= v), row o = quad*4+r (+16)
    const int vv = tile * 16 + vloc;
    if (vv < NV) {
        const float m = nzw ? 1.0f : 0.0f;
        float* ob = out + (size_t)b * (COUT * NV) + vv;
        #pragma unroll
        for (int r = 0; r < 4; ++r) {
            ob[(size_t)(quad * 4 + r) * NV]      = (c0[r] + bs0[r]) * m;
            ob[(size_t)(quad * 4 + 16 + r) * NV] = (c1[r] + bs1[r]) * m;
        }
    }
}

// ---------------------------------------------------------------------------
extern "C" void kernel_launch(void* const* d_in, const int* in_sizes, int n_in,
                              void* d_out, int out_size, void* d_ws, size_t ws_size,
                              hipStream_t stream)
{
    const float* x     = (const float*)d_in[0];
    const int*   index = (const int*)  d_in[1];
    const float* itp   = (const float*)d_in[2];
    const float* w     = (const float*)d_in[3];
    const float* bias  = (const float*)d_in[4];
    float*       out   = (float*)d_out;

    unsigned short* xt  = (unsigned short*)d_ws;                 // 10.5 MB
    unsigned short* wbf = (unsigned short*)((char*)d_ws + (size_t)NV * 256);

    hipLaunchKernelGGL(convert_w_bf16, dim3((COUT * CIN * NK + 255) / 256),
                       dim3(256), 0, stream, w, wbf);
    const int vtiles = (NV + VT - 1) / VT;   // 161
    hipLaunchKernelGGL(transpose_x_bf16, dim3(vtiles * NBS), dim3(256), 0,
                       stream, x, (unsigned*)xt);
    hipLaunchKernelGGL(sparse_conv_mfma, dim3(NT), dim3(256), 0,
                       stream, xt, index, itp, wbf, bias, out);
}